// Round 1
// 2313.950 us; speedup vs baseline: 2.2992x; 2.2992x over previous
//
#include <hip/hip_runtime.h>

#define M_DIM 16384
#define K_DIM 768
#define N_DIM 12288
#define TOPK  32

typedef float f32x4 __attribute__((ext_vector_type(4)));
typedef short s16x8 __attribute__((ext_vector_type(8)));

__device__ __forceinline__ unsigned f2u(float f) {
  union { float f; unsigned u; } v; v.f = f; return v.u;
}
__device__ __forceinline__ float u2f(unsigned u) {
  union { unsigned u; float f; } v; v.u = u; return v.f;
}

// bf16 round-to-nearest-even, returns high 16 bits of fp32
__device__ __forceinline__ unsigned short bf16_rne(float f) {
  unsigned u = f2u(f);
  return (unsigned short)((u + 0x7FFFu + ((u >> 16) & 1u)) >> 16);
}

// ---------------------------------------------------------------------------
// Kernel A: split fp32 -> (hi, lo) bf16 planes.  x = hi + lo + O(2^-18 x)
// ---------------------------------------------------------------------------
__global__ __launch_bounds__(256) void split_bf16_planes(
    const float* __restrict__ src, unsigned short* __restrict__ hi,
    unsigned short* __restrict__ lo, int n4)
{
  const int stride = (int)(gridDim.x * blockDim.x);
  for (int i = (int)(blockIdx.x * blockDim.x + threadIdx.x); i < n4; i += stride) {
    const float4 v = ((const float4*)src)[i];
    ushort4 h, l;
    h.x = bf16_rne(v.x); h.y = bf16_rne(v.y); h.z = bf16_rne(v.z); h.w = bf16_rne(v.w);
    l.x = bf16_rne(v.x - u2f((unsigned)h.x << 16));
    l.y = bf16_rne(v.y - u2f((unsigned)h.y << 16));
    l.z = bf16_rne(v.z - u2f((unsigned)h.z << 16));
    l.w = bf16_rne(v.w - u2f((unsigned)h.w << 16));
    ((ushort4*)hi)[i] = h;
    ((ushort4*)lo)[i] = l;
  }
}

// ---------------------------------------------------------------------------
// Kernel B (main): z = x @ enc_w^T + enc_b via bf16x3 MFMA (fp32-equivalent).
// 128x128 tile, BK=32, 256 threads = 4 waves, each wave 64x64 (4x4 frags of
// 16x16x32).  global_load_lds width-16 staging with pre-swizzled global
// source (XOR k-chunk swizzle -> 2-way max bank aliasing on ds_read_b128).
// ---------------------------------------------------------------------------
__device__ __forceinline__ void mfma16(f32x4& d, s16x8 a, s16x8 b) {
  asm("v_mfma_f32_16x16x32_bf16 %0, %1, %2, %0" : "+v"(d) : "v"(a), "v"(b));
}

#define GL16(g, l) __builtin_amdgcn_global_load_lds(                      \
    (const __attribute__((address_space(1))) void*)(g),                   \
    (__attribute__((address_space(3))) void*)(l), 16, 0, 0)

__global__ __launch_bounds__(256, 2) void TopKSparseAutoencoder_51917564674099_kernel(
    const unsigned short* __restrict__ Ahi, const unsigned short* __restrict__ Alo,
    const unsigned short* __restrict__ Bhi, const unsigned short* __restrict__ Blo,
    const float* __restrict__ bias, float* __restrict__ Z)
{
  // planes: 0=Ahi 1=Alo 2=Bhi 3=Blo ; [row 0..127][k 0..31] bf16 = 8KB each
  __shared__ unsigned short lds[4][128][32];   // 32 KB

  const int t    = (int)threadIdx.x;
  const int wid  = t >> 6;
  const int lane = t & 63;

  // XCD-aware bijective swizzle (nwg = 96*128 = 12288, divisible by 8)
  const int bid  = (int)(blockIdx.y * gridDim.x + blockIdx.x);
  const int bswz = (bid & 7) * (12288 / 8) + (bid >> 3);
  const int n0   = (bswz % 96) * 128;
  const int m0   = (bswz / 96) * 128;

  // ---- staging geometry: wave stages tile rows [32*wid, 32*wid+32) of all
  // planes.  Chunk = 16 rows = 1KB; lane i -> row (i>>2), 16B k-chunk (i&3).
  // LDS is written linearly; the XOR swizzle s(r) = (r>>1)&3 is applied by
  // permuting the GLOBAL source k-chunk (physical slot p holds logical p^s).
  const int rr  = lane >> 2;
  const int kq  = lane & 3;
  const int rt0 = wid * 32 + rr;
  const int rt1 = rt0 + 16;
  const int kc0 = (kq ^ ((rt0 >> 1) & 3)) * 8;   // logical k-chunk * 8 elems
  const int kc1 = (kq ^ ((rt1 >> 1) & 3)) * 8;
  const size_t offA0 = (size_t)(m0 + rt0) * K_DIM + kc0;
  const size_t offA1 = (size_t)(m0 + rt1) * K_DIM + kc1;
  const size_t offB0 = (size_t)(n0 + rt0) * K_DIM + kc0;
  const size_t offB1 = (size_t)(n0 + rt1) * K_DIM + kc1;

  const int wm = (wid >> 1) * 64;   // wave's 64x64 output origin
  const int wn = (wid & 1) * 64;
  const int lr = lane & 15;
  const int lc = lane >> 4;

  f32x4 acc[4][4];
#pragma unroll
  for (int i = 0; i < 4; ++i)
#pragma unroll
    for (int j = 0; j < 4; ++j) acc[i][j] = (f32x4){0.f, 0.f, 0.f, 0.f};

  for (int k0 = 0; k0 < K_DIM; k0 += 32) {
    GL16(Ahi + offA0 + k0, &lds[0][wid * 32][0]);
    GL16(Ahi + offA1 + k0, &lds[0][wid * 32 + 16][0]);
    GL16(Alo + offA0 + k0, &lds[1][wid * 32][0]);
    GL16(Alo + offA1 + k0, &lds[1][wid * 32 + 16][0]);
    GL16(Bhi + offB0 + k0, &lds[2][wid * 32][0]);
    GL16(Bhi + offB1 + k0, &lds[2][wid * 32 + 16][0]);
    GL16(Blo + offB0 + k0, &lds[3][wid * 32][0]);
    GL16(Blo + offB1 + k0, &lds[3][wid * 32 + 16][0]);
    __syncthreads();   // compiler drains vmcnt before s_barrier

    s16x8 ah[4], al[4], bh[4], bl[4];
#pragma unroll
    for (int i = 0; i < 4; ++i) {
      const int r = wm + i * 16 + lr;
      const int p = (lc ^ ((r >> 1) & 3)) * 8;   // swizzled read
      ah[i] = *(const s16x8*)&lds[0][r][p];
      al[i] = *(const s16x8*)&lds[1][r][p];
    }
#pragma unroll
    for (int j = 0; j < 4; ++j) {
      const int r = wn + j * 16 + lr;
      const int p = (lc ^ ((r >> 1) & 3)) * 8;
      bh[j] = *(const s16x8*)&lds[2][r][p];
      bl[j] = *(const s16x8*)&lds[3][r][p];
    }
#pragma unroll
    for (int i = 0; i < 4; ++i)
#pragma unroll
      for (int j = 0; j < 4; ++j) {
        mfma16(acc[i][j], ah[i], bh[j]);   // hi*hi
        mfma16(acc[i][j], ah[i], bl[j]);   // hi*lo
        mfma16(acc[i][j], al[i], bh[j]);   // lo*hi
      }
    __syncthreads();
  }

  asm volatile("s_nop 7\n\ts_nop 7" :::);   // MFMA -> VALU read hazard guard

  // epilogue: C/D layout col = lane&15, row = (lane>>4)*4 + q
#pragma unroll
  for (int j = 0; j < 4; ++j) {
    const int col = n0 + wn + j * 16 + lr;
    const float bb = bias[col];
#pragma unroll
    for (int i = 0; i < 4; ++i) {
      const int r0 = m0 + wm + i * 16 + lc * 4;
#pragma unroll
      for (int q = 0; q < 4; ++q)
        Z[(size_t)(r0 + q) * N_DIM + col] = acc[i][j][q] + bb;
    }
  }
}

// ---------------------------------------------------------------------------
// Kernel B-fallback: fp32 VALU GEMM (used only when workspace is too small)
// ---------------------------------------------------------------------------
__global__ void enc_gemm_f32_fb(
    const float* A, const float* B, const float* bias, float* Z)
{
  __shared__ float As[32][132];
  __shared__ float Bs[32][132];

  const int tx = (int)threadIdx.x;
  const int ty = (int)threadIdx.y;
  const int t  = ty * 16 + tx;
  const int n0 = (int)blockIdx.x * 128;
  const int m0 = (int)blockIdx.y * 128;
  const int r = t >> 1;
  const int h = (t & 1) * 16;

  float c[8][8];
#pragma unroll
  for (int i = 0; i < 8; ++i)
#pragma unroll
    for (int j = 0; j < 8; ++j) c[i][j] = 0.0f;

  for (int k0 = 0; k0 < K_DIM; k0 += 32) {
    const float* pa = A + (size_t)(m0 + r) * K_DIM + k0 + h;
    const float* pb = B + (size_t)(n0 + r) * K_DIM + k0 + h;
    float fa[16], fb[16];
#pragma unroll
    for (int j = 0; j < 16; ++j) fa[j] = pa[j];
#pragma unroll
    for (int j = 0; j < 16; ++j) fb[j] = pb[j];
#pragma unroll
    for (int j = 0; j < 16; ++j) As[h + j][r] = fa[j];
#pragma unroll
    for (int j = 0; j < 16; ++j) Bs[h + j][r] = fb[j];
    __syncthreads();

    for (int kk = 0; kk < 32; ++kk) {
      float av[8], bv[8];
#pragma unroll
      for (int i = 0; i < 8; ++i) av[i] = As[kk][ty * 8 + i];
#pragma unroll
      for (int j = 0; j < 8; ++j) bv[j] = Bs[kk][tx * 8 + j];
#pragma unroll
      for (int i = 0; i < 8; ++i)
#pragma unroll
        for (int j = 0; j < 8; ++j) c[i][j] += av[i] * bv[j];
    }
    __syncthreads();
  }

#pragma unroll
  for (int j = 0; j < 8; ++j) {
    const int col = n0 + tx * 8 + j;
    const float bb = bias[col];
#pragma unroll
    for (int i = 0; i < 8; ++i)
      Z[(size_t)(m0 + ty * 8 + i) * N_DIM + col] = c[i][j] + bb;
  }
}

// ---------------------------------------------------------------------------
// Kernel C: dec_w (768 x 12288) -> dec_wT (12288 x 768), fp32
// ---------------------------------------------------------------------------
__global__ void transpose_decw(const float* W, float* WT)
{
  __shared__ float tile[32][33];
  const int bx = (int)blockIdx.x;
  const int by = (int)blockIdx.y;
  const int tx = (int)threadIdx.x;
  const int ty = (int)threadIdx.y;
#pragma unroll
  for (int j = 0; j < 32; j += 8)
    tile[ty + j][tx] = W[(size_t)(by * 32 + ty + j) * N_DIM + bx * 32 + tx];
  __syncthreads();
#pragma unroll
  for (int j = 0; j < 32; j += 8)
    WT[(size_t)(bx * 32 + ty + j) * K_DIM + by * 32 + tx] = tile[tx][ty + j];
}

// ---------------------------------------------------------------------------
// Kernel D: exact top-32 threshold via register-resident 32-step binary
// search on order-preserving u32 keys (no LDS staging, no atomics in the
// hot path), relu(z - thresh) written in place, compact, sparse decode.
// One 256-thread block per row; each thread holds 48 keys in VGPRs.
// ---------------------------------------------------------------------------
__global__ __launch_bounds__(256, 4) void topk_select_decode(
    float* Z,          // in: raw z, out: z_sparse (M x N)
    const float* __restrict__ WT,   // dec_wT (N x K), valid if use_wt
    const float* __restrict__ DW,   // dec_w  (K x N), fallback
    const float* __restrict__ db,   // dec_b  (K)
    float* __restrict__ XR,         // x_recon (M x K)
    int use_wt)
{
  __shared__ unsigned wcnt[2][4];
  __shared__ int s_nnz;
  __shared__ int   s_col[TOPK];
  __shared__ float s_val[TOPK];

  const int row  = (int)blockIdx.x;
  const int t    = (int)threadIdx.x;
  const int lane = t & 63;
  const int wid  = t >> 6;

  float4* zv = (float4*)(Z + (size_t)row * N_DIM);

  // load row into registers as monotone keys (thread t owns float4s t+256j)
  unsigned kk[48];
#pragma unroll
  for (int j = 0; j < 12; ++j) {
    const float4 v = zv[t + 256 * j];
    unsigned u;
    u = f2u(v.x); kk[4 * j + 0] = u ^ (unsigned)(((int)u >> 31) | 0x80000000);
    u = f2u(v.y); kk[4 * j + 1] = u ^ (unsigned)(((int)u >> 31) | 0x80000000);
    u = f2u(v.z); kk[4 * j + 2] = u ^ (unsigned)(((int)u >> 31) | 0x80000000);
    u = f2u(v.w); kk[4 * j + 3] = u ^ (unsigned)(((int)u >> 31) | 0x80000000);
  }
  if (t == 0) s_nnz = 0;

  // invariant: count(key > lo) >= 32, count(key > hi) < 32; T = final hi
  unsigned lo = 0u, hi = 0xFFFFFFFFu;
  for (int it = 0; it < 32; ++it) {
    const unsigned mid = lo + ((hi - lo) >> 1);
    unsigned c = 0;
#pragma unroll
    for (int q = 0; q < 48; ++q) c += (kk[q] > mid) ? 1u : 0u;
    c += __shfl_down(c, 32);
    c += __shfl_down(c, 16);
    c += __shfl_down(c, 8);
    c += __shfl_down(c, 4);
    c += __shfl_down(c, 2);
    c += __shfl_down(c, 1);
    if (lane == 0) wcnt[it & 1][wid] = c;
    __syncthreads();   // parity-buffered: 1 barrier per iteration is safe
    const unsigned tot = wcnt[it & 1][0] + wcnt[it & 1][1] +
                         wcnt[it & 1][2] + wcnt[it & 1][3];
    if (tot >= (unsigned)TOPK) lo = mid; else hi = mid;
  }
  const unsigned T = hi;                       // exact 32nd-largest key
  const float thresh = u2f((T & 0x80000000u) ? (T ^ 0x80000000u) : ~T);

  // relu(z - thresh) from registers; compact strictly-greater (<= 31 entries)
#define COMP(Q, FLD) {                                                        \
      const unsigned key = kk[4 * j + Q];                                     \
      float v = 0.0f;                                                         \
      if (key > T) {                                                          \
        v = u2f((key & 0x80000000u) ? (key ^ 0x80000000u) : ~key) - thresh;   \
        const int p = atomicAdd(&s_nnz, 1);                                   \
        if (p < TOPK) { s_col[p] = base + Q; s_val[p] = v; }                  \
      }                                                                       \
      o.FLD = v; }
#pragma unroll
  for (int j = 0; j < 12; ++j) {
    float4 o;
    const int base = (t + 256 * j) * 4;
    COMP(0, x)
    COMP(1, y)
    COMP(2, z)
    COMP(3, w)
    zv[t + 256 * j] = o;
  }
#undef COMP
  __syncthreads();

  // sparse decode: x_recon[row][i] = sum_j val_j * dec_w[i][col_j] + dec_b[i]
  const int nnz = (s_nnz < TOPK) ? s_nnz : TOPK;
  float a0 = 0.0f, a1 = 0.0f, a2 = 0.0f;
  if (use_wt) {
    for (int j = 0; j < nnz; ++j) {
      const float v = s_val[j];
      const float* w = WT + (size_t)s_col[j] * K_DIM;
      a0 += v * w[t];
      a1 += v * w[t + 256];
      a2 += v * w[t + 512];
    }
  } else {
    for (int j = 0; j < nnz; ++j) {
      const float v = s_val[j];
      const int col = s_col[j];
      a0 += v * DW[(size_t)(t)       * N_DIM + col];
      a1 += v * DW[(size_t)(t + 256) * N_DIM + col];
      a2 += v * DW[(size_t)(t + 512) * N_DIM + col];
    }
  }
  float* xr = XR + (size_t)row * K_DIM;
  xr[t]       = a0 + db[t];
  xr[t + 256] = a1 + db[t + 256];
  xr[t + 512] = a2 + db[t + 512];
}

// ---------------------------------------------------------------------------
extern "C" void kernel_launch(void* const* d_in, const int* in_sizes, int n_in,
                              void* d_out, int out_size, void* d_ws, size_t ws_size,
                              hipStream_t stream)
{
  (void)in_sizes; (void)n_in; (void)out_size;

  const float* x     = (const float*)d_in[0];
  const float* enc_w = (const float*)d_in[1];
  const float* enc_b = (const float*)d_in[2];
  const float* dec_w = (const float*)d_in[3];
  const float* dec_b = (const float*)d_in[4];
  // d_in[5] = k (constant 32, hardcoded as TOPK)

  float* out     = (float*)d_out;
  float* x_recon = out;                            // M*K floats
  float* z_sp    = out + (size_t)M_DIM * K_DIM;    // M*N floats

  const size_t WT_BYTES = (size_t)N_DIM * K_DIM * sizeof(float);      // 37.75 MB
  const size_t XPLANE   = (size_t)M_DIM * K_DIM * sizeof(unsigned short);
  const size_t WPLANE   = (size_t)N_DIM * K_DIM * sizeof(unsigned short);
  const size_t FULL     = WT_BYTES + 2 * XPLANE + 2 * WPLANE;         // 120 MiB

  char* ws = (char*)d_ws;
  const int use_wt   = (ws_size >= WT_BYTES) ? 1 : 0;
  const int use_mfma = (ws_size >= FULL) ? 1 : 0;

  float*          WT  = (float*)ws;
  unsigned short* xhi = (unsigned short*)(ws + WT_BYTES);
  unsigned short* xlo = (unsigned short*)(ws + WT_BYTES + XPLANE);
  unsigned short* whi = (unsigned short*)(ws + WT_BYTES + 2 * XPLANE);
  unsigned short* wlo = (unsigned short*)(ws + WT_BYTES + 2 * XPLANE + WPLANE);

  if (use_wt) {
    dim3 tb(32, 8);
    dim3 tg(N_DIM / 32, K_DIM / 32);
    transpose_decw<<<tg, tb, 0, stream>>>(dec_w, WT);
  }

  if (use_mfma) {
    split_bf16_planes<<<1024, 256, 0, stream>>>(x, xhi, xlo, M_DIM * K_DIM / 4);
    split_bf16_planes<<<1024, 256, 0, stream>>>(enc_w, whi, wlo, N_DIM * K_DIM / 4);
    dim3 tg(N_DIM / 128, M_DIM / 128);   // (96, 128)
    TopKSparseAutoencoder_51917564674099_kernel<<<tg, 256, 0, stream>>>(
        xhi, xlo, whi, wlo, enc_b, z_sp);
  } else {
    dim3 tb(16, 16);
    dim3 tg(N_DIM / 128, M_DIM / 128);
    enc_gemm_f32_fb<<<tg, tb, 0, stream>>>(x, enc_w, enc_b, z_sp);
  }

  topk_select_decode<<<M_DIM, 256, 0, stream>>>(z_sp, WT, dec_w, dec_b, x_recon, use_wt);
}